// Round 8
// baseline (118.711 us; speedup 1.0000x reference)
//
#include <hip/hip_runtime.h>
#include <hip/hip_bf16.h>

#define NB 2048     // batch rows
#define NL 64       // latent dim
#define NN 16       // nuisance dim
#define NROW 80     // NL + NN
#define NO 2048     // output dim
#define RPB 8       // rows per group
#define MAXG (NB / RPB + NN)   // 272 max groups

typedef unsigned int   u32;
typedef unsigned short u16;

struct Group { int id; int start; int nr; int pad; };

__device__ __forceinline__ float bflo(u32 u) { union { u32 i; float f; } c; c.i = u << 16;         return c.f; }
__device__ __forceinline__ float bfhi(u32 u) { union { u32 i; float f; } c; c.i = u & 0xffff0000u; return c.f; }
__device__ __forceinline__ u16 f2bf(float f) { __hip_bfloat16 h = __float2bfloat16(f); return *(u16*)&h; }

// ---- Pass 0+1 fused: block 0 buckets rows + theta; blocks 1..1024 build M ----
// M[id][l][o] = bf16(W[l][o] + A[id][l][o])
__global__ __launch_bounds__(512) void prep(
    const float* __restrict__ z, const float* __restrict__ pxr,
    const float* __restrict__ W, const float* __restrict__ A,
    u16* __restrict__ M, int* __restrict__ perm, Group* __restrict__ groups,
    int* __restrict__ ngroups, float* __restrict__ out)
{
    const int tid = threadIdx.x;

    if (blockIdx.x != 0) {               // ---- builder blocks ----
        size_t i = ((size_t)(blockIdx.x - 1) * 512 + tid) * 4;
        float4 w = *(const float4*)(W + (i & (size_t)(NL * NO - 1)));
        float4 a = *(const float4*)(A + i);
        ushort4 m;
        m.x = f2bf(w.x + a.x); m.y = f2bf(w.y + a.y);
        m.z = f2bf(w.z + a.z); m.w = f2bf(w.w + a.w);
        *(ushort4*)(M + i) = m;
        return;
    }

    // ---- bucket block ----
    __shared__ int cnt[NN], start_s[NN], cur[NN], gbase_s[NN];
    __shared__ int ids_sh[NB];           // 8 KB

    if (tid < NN) cnt[tid] = 0;
    for (int o = tid; o < NO; o += 512)  // theta = exp(px_r)
        out[(size_t)NB * NO + o] = __expf(pxr[o]);
    __syncthreads();

    // argmax ids: 4 lanes per row, each reads one aligned float4 of the 16 nuisance floats
    const int c = tid & 3;
    #pragma unroll 4
    for (int pass = 0; pass < 16; ++pass) {
        const int row = pass * 128 + (tid >> 2);
        float4 v = *(const float4*)(z + (size_t)row * NROW + NL + c * 4);
        float bv = v.x; int bp = c * 4;
        if (v.y > bv) { bv = v.y; bp = c * 4 + 1; }
        if (v.z > bv) { bv = v.z; bp = c * 4 + 2; }
        if (v.w > bv) { bv = v.w; bp = c * 4 + 3; }
        #pragma unroll
        for (int d = 1; d <= 2; d <<= 1) {          // combine 4 lanes, first-max tie-break
            float ov = __shfl_xor(bv, d);
            int   op = __shfl_xor(bp, d);
            if (ov > bv || (ov == bv && op < bp)) { bv = ov; bp = op; }
        }
        if (c == 0) { ids_sh[row] = bp; atomicAdd(&cnt[bp], 1); }
    }
    __syncthreads();

    if (tid == 0) {                       // prefix + group bases
        int acc = 0, g = 0;
        for (int i = 0; i < NN; ++i) {
            start_s[i] = acc; cur[i] = acc; gbase_s[i] = g;
            acc += cnt[i]; g += (cnt[i] + RPB - 1) / RPB;
        }
        *ngroups = g;
    }
    __syncthreads();

    #pragma unroll
    for (int k = 0; k < NB / 512; ++k) {  // scatter perm (order within bucket arbitrary)
        const int row = tid + k * 512;
        const int id  = ids_sh[row];
        const int pos = atomicAdd(&cur[id], 1);
        perm[pos] = row;
    }
    if (tid < NN) {                       // group table
        const int cn = cnt[tid], s = start_s[tid], gb = gbase_s[tid];
        for (int j = 0; j * RPB < cn; ++j) {
            Group gr; gr.id = tid; gr.start = s + j * RPB;
            gr.nr = min(RPB, cn - j * RPB); gr.pad = 0;
            groups[gb + j] = gr;
        }
    }
}

// ---- Pass 2: fused grouped GEMM + softmax. 8 rows x 2048 cols per 256-thr block,
//      8 cols/thread, one uint4 (8 bf16) load per l-step: 64 FMA per 16B load ----
__global__ __launch_bounds__(256) void gemm_fused(
    const float* __restrict__ z, const float* __restrict__ sf,
    const u16* __restrict__ M, const float* __restrict__ offs,
    const int* __restrict__ perm, const Group* __restrict__ groups,
    const int* __restrict__ ngroups, float* __restrict__ out)
{
    const int g = blockIdx.x;
    if (g >= *ngroups) return;
    const int id     = groups[g].id;
    const int pstart = groups[g].start;
    const int nr     = groups[g].nr;
    const int tid    = threadIdx.x;
    const int lane   = tid & 63, wave = tid >> 6;   // 4 waves

    __shared__ int   rows_s[RPB];
    __shared__ float zT[NL][RPB];
    __shared__ float sfs[RPB];
    __shared__ float red[4][RPB];
    __shared__ float gmax[RPB], gsum[RPB];

    if (tid < RPB) rows_s[tid] = perm[pstart + (tid < nr ? tid : nr - 1)];
    __syncthreads();
    {   // zT: 512 floats, two per thread; lanes cover consecutive l of one row (coalesced)
        int r = tid >> 6, l = tid & 63;
        zT[l][r] = z[(size_t)rows_s[r] * NROW + l];
        int i2 = tid + 256; r = i2 >> 6; l = i2 & 63;
        zT[l][r] = z[(size_t)rows_s[r] * NROW + l];
    }
    if (tid < RPB) sfs[tid] = sf[rows_s[tid]];
    __syncthreads();

    const int c0 = tid * 8;
    const uint4* Mg = (const uint4*)(M + (size_t)id * NL * NO + c0);  // 256 uint4 per l-row

    float acc[RPB][8];
    {
        float4 oa = *(const float4*)(offs + id * NO + c0);
        float4 ob = *(const float4*)(offs + id * NO + c0 + 4);
        #pragma unroll
        for (int r = 0; r < RPB; ++r) {
            acc[r][0] = oa.x; acc[r][1] = oa.y; acc[r][2] = oa.z; acc[r][3] = oa.w;
            acc[r][4] = ob.x; acc[r][5] = ob.y; acc[r][6] = ob.z; acc[r][7] = ob.w;
        }
    }

    #pragma unroll 4
    for (int l = 0; l < NL; ++l) {
        uint4 m = Mg[l * (NO / 8)];                       // 8 bf16, 16B coalesced
        float v0 = bflo(m.x), v1 = bfhi(m.x), v2 = bflo(m.y), v3 = bfhi(m.y);
        float v4 = bflo(m.z), v5 = bfhi(m.z), v6 = bflo(m.w), v7 = bfhi(m.w);
        float4 za = *(const float4*)&zT[l][0];            // LDS broadcast
        float4 zb = *(const float4*)&zT[l][4];
        #define ROWFMA(r, zl) \
            acc[r][0] += (zl) * v0; acc[r][1] += (zl) * v1; acc[r][2] += (zl) * v2; acc[r][3] += (zl) * v3; \
            acc[r][4] += (zl) * v4; acc[r][5] += (zl) * v5; acc[r][6] += (zl) * v6; acc[r][7] += (zl) * v7;
        ROWFMA(0, za.x) ROWFMA(1, za.y) ROWFMA(2, za.z) ROWFMA(3, za.w)
        ROWFMA(4, zb.x) ROWFMA(5, zb.y) ROWFMA(6, zb.z) ROWFMA(7, zb.w)
        #undef ROWFMA
    }

    // ---- block max per row ----
    float rv[RPB];
    #pragma unroll
    for (int r = 0; r < RPB; ++r) {
        float mv = acc[r][0];
        #pragma unroll
        for (int cc = 1; cc < 8; ++cc) mv = fmaxf(mv, acc[r][cc]);
        #pragma unroll
        for (int off = 32; off > 0; off >>= 1) mv = fmaxf(mv, __shfl_down(mv, off));
        rv[r] = mv;
    }
    if (lane == 0) {
        for (int r = 0; r < RPB; ++r) red[wave][r] = rv[r];
    }
    __syncthreads();
    if (tid < RPB) {
        float mm = fmaxf(fmaxf(red[0][tid], red[1][tid]), fmaxf(red[2][tid], red[3][tid]));
        gmax[tid] = mm;
    }
    __syncthreads();

    // ---- exp + block sum per row ----
    #pragma unroll
    for (int r = 0; r < RPB; ++r) {
        const float mx = gmax[r];
        float s = 0.f;
        #pragma unroll
        for (int cc = 0; cc < 8; ++cc) { acc[r][cc] = __expf(acc[r][cc] - mx); s += acc[r][cc]; }
        #pragma unroll
        for (int off = 32; off > 0; off >>= 1) s += __shfl_down(s, off);
        rv[r] = s;
    }
    if (lane == 0) {
        for (int r = 0; r < RPB; ++r) red[wave][r] = rv[r];
    }
    __syncthreads();
    if (tid < RPB) {
        gsum[tid] = (red[0][tid] + red[1][tid]) + (red[2][tid] + red[3][tid]);
    }
    __syncthreads();

    for (int r = 0; r < nr; ++r) {
        const float scl = sfs[r] / gsum[r];
        float* op = out + (size_t)rows_s[r] * NO + c0;
        *(float4*)(op)     = make_float4(acc[r][0] * scl, acc[r][1] * scl, acc[r][2] * scl, acc[r][3] * scl);
        *(float4*)(op + 4) = make_float4(acc[r][4] * scl, acc[r][5] * scl, acc[r][6] * scl, acc[r][7] * scl);
    }
}

// ---- Fallback (ws too small): row-per-block fp32 path ----
__global__ __launch_bounds__(256) void decoder_f(
    const float* __restrict__ z, const float* __restrict__ sf,
    const float* __restrict__ W, const float* __restrict__ A,
    const float* __restrict__ offs, const float* __restrict__ pxr,
    float* __restrict__ out)
{
    const int b   = blockIdx.x;
    const int tid = threadIdx.x;
    if (b == NB) {
        for (int o = tid; o < NO; o += 256) out[(size_t)NB * NO + o] = __expf(pxr[o]);
        return;
    }
    __shared__ float z0s[NL];
    __shared__ int   s_id;
    __shared__ float s_red[6];
    if (tid < NL) z0s[tid] = z[b * NROW + tid];
    if (tid == 0) {
        float best = -1e30f; int bi = 0;
        for (int i = 0; i < NN; ++i) { float v = z[b * NROW + NL + i]; if (v > best) { best = v; bi = i; } }
        s_id = bi;
    }
    __syncthreads();
    const int id = s_id;
    const int o0 = tid * 8;
    const float* wp = W + o0;
    const float* ap = A + (size_t)id * NL * NO + o0;
    float acc[8];
    {
        float4 oa = *(const float4*)(offs + id * NO + o0);
        float4 ob = *(const float4*)(offs + id * NO + o0 + 4);
        acc[0]=oa.x; acc[1]=oa.y; acc[2]=oa.z; acc[3]=oa.w;
        acc[4]=ob.x; acc[5]=ob.y; acc[6]=ob.z; acc[7]=ob.w;
    }
    #pragma unroll 4
    for (int l = 0; l < NL; ++l) {
        const float zl = z0s[l];
        float4 w0 = *(const float4*)(wp + l * NO);
        float4 w1 = *(const float4*)(wp + l * NO + 4);
        float4 a0 = *(const float4*)(ap + l * NO);
        float4 a1 = *(const float4*)(ap + l * NO + 4);
        acc[0] += zl * (w0.x + a0.x); acc[1] += zl * (w0.y + a0.y);
        acc[2] += zl * (w0.z + a0.z); acc[3] += zl * (w0.w + a0.w);
        acc[4] += zl * (w1.x + a1.x); acc[5] += zl * (w1.y + a1.y);
        acc[6] += zl * (w1.z + a1.z); acc[7] += zl * (w1.w + a1.w);
    }
    float m = acc[0];
    #pragma unroll
    for (int j = 1; j < 8; ++j) m = fmaxf(m, acc[j]);
    #pragma unroll
    for (int off = 32; off > 0; off >>= 1) m = fmaxf(m, __shfl_down(m, off));
    if ((tid & 63) == 0) s_red[tid >> 6] = m;
    __syncthreads();
    if (tid == 0) s_red[4] = fmaxf(fmaxf(s_red[0], s_red[1]), fmaxf(s_red[2], s_red[3]));
    __syncthreads();
    const float mx = s_red[4];
    float ex[8];
    float s = 0.f;
    #pragma unroll
    for (int j = 0; j < 8; ++j) { ex[j] = __expf(acc[j] - mx); s += ex[j]; }
    #pragma unroll
    for (int off = 32; off > 0; off >>= 1) s += __shfl_down(s, off);
    if ((tid & 63) == 0) s_red[tid >> 6] = s;
    __syncthreads();
    if (tid == 0) s_red[5] = (s_red[0] + s_red[1]) + (s_red[2] + s_red[3]);
    __syncthreads();
    const float scale = sf[b] / s_red[5];
    float* op = out + (size_t)b * NO + o0;
    *(float4*)(op)     = make_float4(ex[0]*scale, ex[1]*scale, ex[2]*scale, ex[3]*scale);
    *(float4*)(op + 4) = make_float4(ex[4]*scale, ex[5]*scale, ex[6]*scale, ex[7]*scale);
}

extern "C" void kernel_launch(void* const* d_in, const int* in_sizes, int n_in,
                              void* d_out, int out_size, void* d_ws, size_t ws_size,
                              hipStream_t stream) {
    const float* z    = (const float*)d_in[0];
    const float* sf   = (const float*)d_in[1];
    const float* W    = (const float*)d_in[2];
    const float* A    = (const float*)d_in[3];
    const float* offs = (const float*)d_in[4];
    const float* pxr  = (const float*)d_in[5];
    float* out = (float*)d_out;

    // ws layout: M 4MiB | perm 8KiB | groups 8KiB | ngroups
    const size_t M_OFF = 0, PERM_OFF = 4u << 20, GRP_OFF = (4u << 20) + 8192,
                 NG_OFF = (4u << 20) + 16384;
    const size_t ws_need = NG_OFF + 256;
    if (ws_size >= ws_need) {
        char* wsb = (char*)d_ws;
        u16*   M       = (u16*)(wsb + M_OFF);
        int*   perm    = (int*)(wsb + PERM_OFF);
        Group* groups  = (Group*)(wsb + GRP_OFF);
        int*   ngroups = (int*)(wsb + NG_OFF);
        // grid: block 0 buckets, blocks 1..1024 build M (2M elems / (512 thr * 4))
        hipLaunchKernelGGL(prep, dim3(1 + (NN * NL * NO / 4) / 512), dim3(512), 0, stream,
                           z, pxr, W, A, M, perm, groups, ngroups, out);
        hipLaunchKernelGGL(gemm_fused, dim3(MAXG), dim3(256), 0, stream,
                           z, sf, M, offs, perm, groups, ngroups, out);
    } else {
        hipLaunchKernelGGL(decoder_f, dim3(NB + 1), dim3(256), 0, stream, z, sf, W, A, offs, pxr, out);
    }
}